// Round 1
// baseline (1240.595 us; speedup 1.0000x reference)
//
#include <hip/hip_runtime.h>
#include <hip/hip_bf16.h>

#define BATCH   16
#define NPTS    4096
#define CIN     256
#define COUT    512
#define KNN     16
#define NOUT    1024
#define XOUT_ELEMS 8388608   // 16*1024*512
#define LDA     40           // padded LDS leading dim (bf16 elems), known-good
#define NFPSBLK 8            // 2 batches per FPS block (skew-2 pipeline)
#define DYN_LDS 20480        // GEMM tiles: 2*128*LDA*2B; FPS needs only 8.3KB

typedef __attribute__((ext_vector_type(4))) float f32x4;
typedef __attribute__((ext_vector_type(2))) float f32x2;
typedef __attribute__((ext_vector_type(8))) short bf16x8;
typedef unsigned long long u64;

__device__ __forceinline__ unsigned short f2bf_rne(float f) {
    unsigned u = __float_as_uint(f);
    return (unsigned short)((u + 0x7FFFu + ((u >> 16) & 1u)) >> 16);
}
__device__ __forceinline__ float bf2f(unsigned short s) {
    return __uint_as_float(((unsigned)s) << 16);
}

// 6-step DPP max-reduce across 64 lanes; lane 63 ends with the max (HW-validated R1).
__device__ __forceinline__ float wave_max_dpp(float v) {
    int x, y;
    x = __float_as_int(v);
    y = __builtin_amdgcn_update_dpp(x, x, 0x111, 0xf, 0xf, false);
    v = fmaxf(v, __int_as_float(y)); x = __float_as_int(v);
    y = __builtin_amdgcn_update_dpp(x, x, 0x112, 0xf, 0xf, false);
    v = fmaxf(v, __int_as_float(y)); x = __float_as_int(v);
    y = __builtin_amdgcn_update_dpp(x, x, 0x114, 0xf, 0xf, false);
    v = fmaxf(v, __int_as_float(y)); x = __float_as_int(v);
    y = __builtin_amdgcn_update_dpp(x, x, 0x118, 0xf, 0xf, false);
    v = fmaxf(v, __int_as_float(y)); x = __float_as_int(v);
    y = __builtin_amdgcn_update_dpp(x, x, 0x142, 0xf, 0xf, false);
    v = fmaxf(v, __int_as_float(y)); x = __float_as_int(v);
    y = __builtin_amdgcn_update_dpp(x, x, 0x143, 0xf, 0xf, false);
    v = fmaxf(v, __int_as_float(y));
    return v;
}

// One 4-j chunk (8 points) of the distance/min/argmax update.
// EXACT numpy f32 arithmetic: contract off (block pragma), ((dx2+dy2)+dz2),
// strict > so earliest index wins within a thread.
#define DIST4(PX, PY, PZ, DD, WX2, WY2, WZ2, BD, BJ, J0)                      \
    _Pragma("unroll")                                                          \
    for (int j = (J0); j < (J0) + 4; ++j) {                                    \
        f32x2 dx = PX[j] - WX2;                                                \
        f32x2 dy = PY[j] - WY2;                                                \
        f32x2 dz = PZ[j] - WZ2;                                                \
        f32x2 s  = ((dx * dx) + (dy * dy)) + (dz * dz);                        \
        f32x2 nd;                                                              \
        nd.x = fminf(DD[j].x, s.x);                                            \
        nd.y = fminf(DD[j].y, s.y);                                            \
        DD[j] = nd;                                                            \
        bool g0 = nd.x > BD;                                                   \
        BD = g0 ? nd.x : BD;                                                   \
        BJ = g0 ? (j << 1) : BJ;                                               \
        bool g1 = nd.y > BD;                                                   \
        BD = g1 ? nd.y : BD;                                                   \
        BJ = g1 ? (j << 1) + 1 : BJ;                                           \
    }

// Wave-level reduce of (bestd,bestj) -> key. Same semantics as the proven R2
// version: DPP max, lane-63 broadcast, ballot+ctz first-occurrence tie-break,
// key = (d_bits<<32) | (NPTS-1-idx) so max-key prefers lowest point index.
#define WAVE_KEY(BD, BJ, KEYOUT)                                               \
    {                                                                          \
        float vmax = wave_max_dpp(BD);                                         \
        float wmax = __int_as_float(                                           \
            __builtin_amdgcn_readlane(__float_as_int(vmax), 63));              \
        u64 msk = __ballot(BD == wmax);                                        \
        int lead = (int)__builtin_ctzll(msk);                                  \
        int wbpi = __builtin_amdgcn_readlane(base + BJ, lead);                 \
        KEYOUT = ((u64)__float_as_uint(wmax) << 32)                            \
               | (unsigned)(NPTS - 1 - wbpi);                                  \
    }

#define SEL4(K0, K1, K2, K3, WOUT)                                             \
    {                                                                          \
        u64 a0 = K0, a1 = K1, a2 = K2, a3 = K3;                                \
        if (a1 > a0) a0 = a1;                                                  \
        if (a3 > a2) a2 = a3;                                                  \
        if (a2 > a0) a0 = a2;                                                  \
        WOUT = NPTS - 1 - (int)(unsigned)(a0 & 0xffffffffull);                 \
    }

// Kernel 1: blocks [0,8) run TWO batches of FPS each (skew-2 software pipeline:
// batch B's distance VALU hides batch A's reduce/barrier/coord-fetch latency
// and vice versa); blocks [8,2056) GEMM.
extern "C" __global__ void __launch_bounds__(256)
fps_gemm(const float* __restrict__ x, const float* __restrict__ p,
         const float* __restrict__ W, const float* __restrict__ bias,
         const float* __restrict__ gamma, const float* __restrict__ beta,
         const float* __restrict__ rmean, const float* __restrict__ rvar,
         int* __restrict__ fid, unsigned short* __restrict__ h,
         float* __restrict__ out)
{
    extern __shared__ char smem[];
    const int t = threadIdx.x;
    const int lane = t & 63;
    const int wv = t >> 6;

    if (blockIdx.x < NFPSBLK) {
        // ---------------- FPS: two batches, half-iteration skew ----------------
#pragma clang fp contract(off)
        const int bA = blockIdx.x << 1, bB = bA | 1;
        u64* warrA = (u64*)smem;                 // [4] wave keys, batch A
        u64* warrB = warrA + 4;                  // [4] wave keys, batch B
        int* winsA = (int*)(smem + 64);          // [1024]
        int* winsB = winsA + NOUT;               // [1024]
        const float* pAp = p + (size_t)bA * NPTS * 3;
        const float* pBp = p + (size_t)bB * NPTS * 3;

        // thread t owns points [16t,16t+16) of each batch; coords live in regs.
        const int base = t << 4;
        f32x2 pxA[8], pyA[8], pzA[8], dA[8];
        f32x2 pxB[8], pyB[8], pzB[8], dB[8];
#pragma unroll
        for (int j = 0; j < 8; ++j) {
            const int p0 = (base + (j << 1)) * 3;
            pxA[j] = (f32x2){pAp[p0],     pAp[p0 + 3]};
            pyA[j] = (f32x2){pAp[p0 + 1], pAp[p0 + 4]};
            pzA[j] = (f32x2){pAp[p0 + 2], pAp[p0 + 5]};
            pxB[j] = (f32x2){pBp[p0],     pBp[p0 + 3]};
            pyB[j] = (f32x2){pBp[p0 + 1], pBp[p0 + 4]};
            pzB[j] = (f32x2){pBp[p0 + 2], pBp[p0 + 5]};
            dA[j] = (f32x2){3.4028235e38f, 3.4028235e38f}; // min(FLT_MAX,d0)==d0
            dB[j] = dA[j];
        }
        if (t == 0) { winsA[0] = 0; winsB[0] = 0; }
        // Fake keys so the first in-loop B-select yields winnerB(0)=0.
        if (t < 4) warrB[t] = (u64)(NPTS - 1);
        // winner(0)=0 coords for A (all threads read same addr -> broadcast).
        float wxA = pAp[0], wyA = pAp[1], wzA = pAp[2];
        float wxB, wyB, wzB;                     // assigned in half A before use
        __syncthreads();

        for (int i = 1; i < NOUT; ++i) {
            // ======== HALF A: produce winnerA(i); overlap B(i-1) select ========
            // issue B key reads first (published by prev iteration's barrier)
            u64 kb0 = warrB[0], kb1 = warrB[1], kb2 = warrB[2], kb3 = warrB[3];
            f32x2 wxA2 = {wxA, wxA}, wyA2 = {wyA, wyA}, wzA2 = {wzA, wzA};
            float bestdA = -1.0f; int bestjA = 0;
            DIST4(pxA, pyA, pzA, dA, wxA2, wyA2, wzA2, bestdA, bestjA, 0)
            // B winner(i-1): select + issue its coord loads (global, L2-hot);
            // the loads stay in flight under the rest of half A.
            int wB; SEL4(kb0, kb1, kb2, kb3, wB)
            if (t == 0) winsB[i - 1] = wB;
            wxB = pBp[(size_t)wB * 3];
            wyB = pBp[(size_t)wB * 3 + 1];
            wzB = pBp[(size_t)wB * 3 + 2];
            DIST4(pxA, pyA, pzA, dA, wxA2, wyA2, wzA2, bestdA, bestjA, 4)
            u64 keyA; WAVE_KEY(bestdA, bestjA, keyA)
            if (lane == 0) warrA[wv] = keyA;
            __syncthreads();                     // publishes keyA(i)

            // ======== HALF B: produce winnerB(i); overlap A(i) select ========
            u64 ka0 = warrA[0], ka1 = warrA[1], ka2 = warrA[2], ka3 = warrA[3];
            f32x2 wxB2 = {wxB, wxB}, wyB2 = {wyB, wyB}, wzB2 = {wzB, wzB};
            float bestdB = -1.0f; int bestjB = 0;
            DIST4(pxB, pyB, pzB, dB, wxB2, wyB2, wzB2, bestdB, bestjB, 0)
            int wA; SEL4(ka0, ka1, ka2, ka3, wA)
            if (t == 0) winsA[i] = wA;
            wxA = pAp[(size_t)wA * 3];
            wyA = pAp[(size_t)wA * 3 + 1];
            wzA = pAp[(size_t)wA * 3 + 2];
            DIST4(pxB, pyB, pzB, dB, wxB2, wyB2, wzB2, bestdB, bestjB, 4)
            u64 keyB; WAVE_KEY(bestdB, bestjB, keyB)
            if (lane == 0) warrB[wv] = keyB;
            __syncthreads();                     // publishes keyB(i)
        }
        // epilogue: resolve winnerB(1023), then bulk-write fid and p_out.
        {
            u64 kb0 = warrB[0], kb1 = warrB[1], kb2 = warrB[2], kb3 = warrB[3];
            int wB; SEL4(kb0, kb1, kb2, kb3, wB)
            if (t == 0) winsB[NOUT - 1] = wB;
        }
        __syncthreads();
        float* poutA = out + XOUT_ELEMS + (size_t)bA * NOUT * 3;
        float* poutB = out + XOUT_ELEMS + (size_t)bB * NOUT * 3;
        for (int i = t; i < NOUT; i += 256) {
            int wa = winsA[i];
            fid[bA * NOUT + i] = bA * NPTS + wa;
            float* poa = poutA + (size_t)i * 3;
            poa[0] = pAp[wa * 3]; poa[1] = pAp[wa * 3 + 1]; poa[2] = pAp[wa * 3 + 2];
            int wb = winsB[i];
            fid[bB * NOUT + i] = bB * NPTS + wb;
            float* pob = poutB + (size_t)i * 3;
            pob[0] = pBp[wb * 3]; pob[1] = pBp[wb * 3 + 1]; pob[2] = pBp[wb * 3 + 2];
        }
    } else {
        // ---------------- GEMM: h = relu(BN(x @ W^T + b)), bf16 MFMA ----------------
        const int bid = blockIdx.x - NFPSBLK;
        const int bm = bid >> 2;           // 512 M-tiles of 128
        const int bn = bid & 3;            // 4 N-tiles of 128
        short* As = (short*)smem;          // [128][LDA]
        short* Bs = As + 128 * LDA;        // [128][LDA] (W is [n][k] = B^T)

        const int wm = wv >> 1, wn = wv & 1;   // 2x2 waves, 64x64 each
        const int quad = lane >> 4, l16 = lane & 15;
        const int m0 = bm * 128, n0 = bn * 128;

        f32x4 acc[4][4];
        const f32x4 zero = {0.0f, 0.0f, 0.0f, 0.0f};
#pragma unroll
        for (int a = 0; a < 4; ++a)
#pragma unroll
            for (int bb = 0; bb < 4; ++bb) acc[a][bb] = zero;

        const int srow = t >> 3;           // 0..31
        const int scol = (t & 7) << 2;     // 0..28

        for (int ks = 0; ks < 8; ++ks) {   // K=256 in steps of 32
            const int k0 = ks * 32;
            __syncthreads();
#pragma unroll
            for (int it = 0; it < 4; ++it) {
                int row = srow + it * 32;
                float4 va = *(const float4*)(x + (size_t)(m0 + row) * CIN + k0 + scol);
                short4 pa = make_short4((short)f2bf_rne(va.x), (short)f2bf_rne(va.y),
                                        (short)f2bf_rne(va.z), (short)f2bf_rne(va.w));
                *(short4*)(As + row * LDA + scol) = pa;
                float4 vb = *(const float4*)(W + (size_t)(n0 + row) * CIN + k0 + scol);
                short4 pb2 = make_short4((short)f2bf_rne(vb.x), (short)f2bf_rne(vb.y),
                                         (short)f2bf_rne(vb.z), (short)f2bf_rne(vb.w));
                *(short4*)(Bs + row * LDA + scol) = pb2;
            }
            __syncthreads();
            bf16x8 af[4], bfr[4];
#pragma unroll
            for (int tm = 0; tm < 4; ++tm)
                af[tm] = *(const bf16x8*)(As + (wm * 64 + tm * 16 + l16) * LDA + quad * 8);
#pragma unroll
            for (int tn = 0; tn < 4; ++tn)
                bfr[tn] = *(const bf16x8*)(Bs + (wn * 64 + tn * 16 + l16) * LDA + quad * 8);
#pragma unroll
            for (int tm = 0; tm < 4; ++tm)
#pragma unroll
                for (int tn = 0; tn < 4; ++tn)
                    acc[tm][tn] = __builtin_amdgcn_mfma_f32_16x16x32_bf16(
                        af[tm], bfr[tn], acc[tm][tn], 0, 0, 0);
        }
#pragma unroll
        for (int tn = 0; tn < 4; ++tn) {
            int c = n0 + wn * 64 + tn * 16 + l16;
            float sc = gamma[c] / sqrtf(rvar[c] + 1e-5f);
            float sh = (bias[c] - rmean[c]) * sc + beta[c];
#pragma unroll
            for (int tm = 0; tm < 4; ++tm) {
                int rbase = m0 + wm * 64 + tm * 16 + quad * 4;
#pragma unroll
                for (int r = 0; r < 4; ++r) {
                    float v = fmaxf(acc[tm][tn][r] * sc + sh, 0.0f);
                    h[(size_t)(rbase + r) * COUT + c] = f2bf_rne(v);
                }
            }
        }
    }
}

// Kernel 2: gather+maxpool (known-good R2/R7 version)
extern "C" __global__ void __launch_bounds__(128)
gather_maxpool(const int* __restrict__ sid32, const int* __restrict__ fid,
               const unsigned short* __restrict__ h, float* __restrict__ out)
{
    const int j = blockIdx.x;     // 0..16383
    const int t = threadIdx.x;
    __shared__ int rows[KNN];
    const int frow = fid[j];
    // sid_euc may be int32 or int64 (JAX x64 ambiguity); sniff high words.
    bool is64 = (sid32[1] == 0) && (sid32[3] == 0) && (sid32[5] == 0);
    if (t < KNN) {
        long long e = (long long)frow * KNN + t;
        rows[t] = is64 ? sid32[e * 2] : sid32[e];
    }
    __syncthreads();

    const int c4 = t << 2;
    float m0 = -3.4028235e38f, m1 = m0, m2 = m0, m3 = m0;
#pragma unroll
    for (int k = 0; k < KNN; ++k) {
        const ushort4 v = *(const ushort4*)(h + (size_t)rows[k] * COUT + c4);
        m0 = fmaxf(m0, bf2f(v.x));
        m1 = fmaxf(m1, bf2f(v.y));
        m2 = fmaxf(m2, bf2f(v.z));
        m3 = fmaxf(m3, bf2f(v.w));
    }
    *(float4*)(out + (size_t)j * COUT + c4) = make_float4(m0, m1, m2, m3);
}

extern "C" void kernel_launch(void* const* d_in, const int* in_sizes, int n_in,
                              void* d_out, int out_size, void* d_ws, size_t ws_size,
                              hipStream_t stream)
{
    const float* x     = (const float*)d_in[0];
    const float* p     = (const float*)d_in[1];
    const int*   sid   = (const int*)d_in[2];   // tid_euc (d_in[3]) unused
    const float* W     = (const float*)d_in[4];
    const float* bias  = (const float*)d_in[5];
    const float* gamma = (const float*)d_in[6];
    const float* beta  = (const float*)d_in[7];
    const float* rmean = (const float*)d_in[8];
    const float* rvar  = (const float*)d_in[9];
    float* out = (float*)d_out;

    int* fid = (int*)d_ws;                                      // [16384] @ 0
    unsigned short* h = (unsigned short*)((char*)d_ws + 65792); // 65536x512 bf16

    hipLaunchKernelGGL(fps_gemm, dim3(NFPSBLK + 2048), dim3(256), DYN_LDS, stream,
                       x, p, W, bias, gamma, beta, rmean, rvar, fid, h, out);
    hipLaunchKernelGGL(gather_maxpool, dim3(BATCH * NOUT), dim3(128), 0, stream,
                       sid, fid, h, out);
}